// Round 9
// baseline (62.779 us; speedup 1.0000x reference)
//
#include <hip/hip_runtime.h>
#include <stdint.h>

// y[m][n] = scales[n] * sum_k x[m][k]*W[n][k] + bias[n]
// M=128, K=4096, N=11008. x fp32; W int8-valued int32 [N][K]; out fp32.
//
// Round-9 structure (barrier-free register-A streaming; r3's proven pipeline
// shape scaled to full-M so B crosses L3 exactly once):
//   pack_x: x fp32 -> bf16 in MFMA A-frag order into ws (1 MiB; L2-resident,
//           shared read stream for all co-resident waves -> L1/L2 served).
//   gemm1w: ONE WAVE per block (64 thr), BM=128 (FULL M, in REGISTERS) x
//           BN=16, ks=4 -> 2752 independent waves (~10.75/CU), no LDS, no
//           barriers. Pipeline at half-chunk (k=32) granularity: named
//           2-buffer LOADH/COMPH interleave (8 A b128-loads + 2 B dwordx4
//           + 8 MFMA per step); compiler inserts dep-based vmcnt. ~130 VGPR,
//           launch_bounds(64,3) -> 12 waves/CU resident >= demand.
//   reduce: out = scales*(sum of 4 partials) + bias (deterministic).

#define M_ROWS 128
#define K_DIM  4096
#define N_DIM  11008
#define CHUNKS 64                       // K chunks of 64
#define NT16   (N_DIM / 16)             // 688 n-tiles
#define XP_BYTES (M_ROWS * K_DIM * 2)   // 1 MiB packed bf16 x
#define PART_ELEMS ((size_t)M_ROWS * (size_t)N_DIM)

typedef __attribute__((ext_vector_type(8))) short bf16x8;
typedef __attribute__((ext_vector_type(4))) float f32x4;

__device__ __forceinline__ unsigned bf16_rn(float f) {
  unsigned u = __float_as_uint(f);
  return (u + 0x7FFFu + ((u >> 16) & 1u)) >> 16;   // round-to-nearest-even
}
// two exact int->f32, pack top halves into 2xbf16 (truncate = exact, |w|<=128)
__device__ __forceinline__ unsigned pk2(int a, int b) {
  unsigned lo = __float_as_uint((float)a), hi = __float_as_uint((float)b);
#if __has_builtin(__builtin_amdgcn_perm)
  return __builtin_amdgcn_perm(hi, lo, 0x07060302u);
#else
  return (hi & 0xFFFF0000u) | (lo >> 16);
#endif
}

// ---------------- pack x: fp32 -> bf16 in A-frag order ----------------
// Chunk kk = 16 KiB: 16B unit u = (mf*2 + s)*64 + lane
// frag (mf,s): lane l holds x[16*mf + (l&15)][kk*64 + s*32 + 8*(l>>4) + j]
__global__ __launch_bounds__(256) void pack_x_kernel(
    const float* __restrict__ x, unsigned short* __restrict__ xp) {
  int tid  = blockIdx.x * 256 + threadIdx.x;   // 65536 threads
  int lane = tid & 63;
  int h    = (tid >> 6) & 1;
  int mf   = (tid >> 7) & 7;
  int kk   = tid >> 10;
  int m     = mf * 16 + (lane & 15);
  int kbase = kk * 64 + h * 32 + ((lane >> 4) * 8);
  const float* src = x + (size_t)m * K_DIM + kbase;
  float4 f0 = *(const float4*)(src);
  float4 f1 = *(const float4*)(src + 4);
  float v[8] = {f0.x, f0.y, f0.z, f0.w, f1.x, f1.y, f1.z, f1.w};
  unsigned po[4];
#pragma unroll
  for (int i = 0; i < 4; ++i)
    po[i] = bf16_rn(v[2 * i]) | (bf16_rn(v[2 * i + 1]) << 16);
  *(uint4*)(xp + (size_t)tid * 8) = *(uint4*)po;
}

// ------------- single-wave GEMM: BM=128 (reg A) x BN=16, no LDS ------------
struct HB { bf16x8 a[8]; uint4 b[2]; };   // one half-chunk (k=32): 40 VGPR

__global__ __launch_bounds__(64, 3) void gemm1w_kernel(
    const unsigned short* __restrict__ xp,
    const int* __restrict__ wq,
    const float* __restrict__ scales,
    const float* __restrict__ bias,
    float* __restrict__ dst,          // ks==1: out, else partials
    int ks) {
  const int lane = threadIdx.x;       // 0..63
  const int nt   = blockIdx.x;        // 0..687
  const int kz   = blockIdx.y;        // 0..ks-1
  const int cpb  = CHUNKS / ks;       // chunks per block
  const int H    = cpb * 2;           // half-chunks per block (even, >=4)
  const int kk0  = kz * cpb;
  const size_t n0 = (size_t)nt * 16;
  const int l15 = lane & 15, lh = lane >> 4;

  // A: half-chunk h, frag mf at byte (kk0 + (h>>1))*16384 + (h&1)*1024
  //    + mf*2048 + lane*16
  const char* agp = (const char*)xp + (size_t)kk0 * 16384 + lane * 16;
  // B: row n0 + l15; half-chunk h ints at (kk0 + (h>>1))*64 + (h&1)*32 + lh*8
  const int* bgp = wq + (n0 + (size_t)l15) * K_DIM + (size_t)kk0 * 64 + lh * 8;

  f32x4 acc[8];
  {
    f32x4 z = {0.f, 0.f, 0.f, 0.f};
#pragma unroll
    for (int i = 0; i < 8; ++i) acc[i] = z;
  }

  auto LOADH = [&](int h, HB& P) {
    const char* ap = agp + ((h >> 1) * 16384 + (h & 1) * 1024);
#pragma unroll
    for (int mf = 0; mf < 8; ++mf)
      P.a[mf] = *(const bf16x8*)(ap + mf * 2048);
    const int* bp = bgp + ((h >> 1) * 64 + (h & 1) * 32);
    P.b[0] = *(const uint4*)(bp);
    P.b[1] = *(const uint4*)(bp + 4);
  };
  auto COMPH = [&](HB& P) {
    union { unsigned u[4]; bf16x8 b; } c;
    c.u[0] = pk2((int)P.b[0].x, (int)P.b[0].y);
    c.u[1] = pk2((int)P.b[0].z, (int)P.b[0].w);
    c.u[2] = pk2((int)P.b[1].x, (int)P.b[1].y);
    c.u[3] = pk2((int)P.b[1].z, (int)P.b[1].w);
#pragma unroll
    for (int mf = 0; mf < 8; ++mf)
      acc[mf] = __builtin_amdgcn_mfma_f32_16x16x32_bf16(P.a[mf], c.b, acc[mf], 0, 0, 0);
  };

  HB P0, P1;
  LOADH(0, P0);
#pragma unroll 1
  for (int h = 0; h < H - 2; h += 2) {
    LOADH(h + 1, P1);
    COMPH(P0);          // P0 = h   (loaded one step earlier; dep-based wait)
    LOADH(h + 2, P0);
    COMPH(P1);          // P1 = h+1
  }
  LOADH(H - 1, P1);
  COMPH(P0);            // H-2
  COMPH(P1);            // H-1

  // epilogue: m = mf*16 + lh*4 + r ; n = n0 + l15
  if (ks == 1) {
    const size_t n = n0 + (size_t)l15;
    const float sc = scales[n], bi = bias[n];
#pragma unroll
    for (int mf = 0; mf < 8; ++mf) {
      const int mb = mf * 16 + lh * 4;
#pragma unroll
      for (int r = 0; r < 4; ++r)
        dst[(size_t)(mb + r) * N_DIM + n] = sc * acc[mf][r] + bi;
    }
  } else {
    float* pb = dst + (size_t)kz * PART_ELEMS + n0 + l15;
#pragma unroll
    for (int mf = 0; mf < 8; ++mf) {
      const int mb = mf * 16 + lh * 4;
#pragma unroll
      for (int r = 0; r < 4; ++r)
        pb[(size_t)(mb + r) * N_DIM] = acc[mf][r];
    }
  }
}

// ---------------- combine partials + epilogue ----------------
__global__ __launch_bounds__(256) void reduce_kernel(
    const float* __restrict__ part, const float* __restrict__ scales,
    const float* __restrict__ bias, float* __restrict__ out, int ks) {
  const int m = blockIdx.y;
  const int c4 = blockIdx.x * 256 + threadIdx.x;
  if (c4 >= N_DIM / 4) return;
  const size_t n = (size_t)c4 * 4;
  const float* p = part + (size_t)m * N_DIM + n;
  float4 s = *(const float4*)(p);
  for (int z = 1; z < ks; ++z) {
    float4 q = *(const float4*)(p + (size_t)z * PART_ELEMS);
    s.x += q.x; s.y += q.y; s.z += q.z; s.w += q.w;
  }
  float4 sc = *(const float4*)(scales + n);
  float4 bi = *(const float4*)(bias + n);
  float4 r;
  r.x = sc.x * s.x + bi.x;
  r.y = sc.y * s.y + bi.y;
  r.z = sc.z * s.z + bi.z;
  r.w = sc.w * s.w + bi.w;
  *(float4*)(out + (size_t)m * N_DIM + n) = r;
}

// ---------------- insurance path if ws is tiny ----------------
__global__ __launch_bounds__(256) void naive_kernel(
    const float* __restrict__ x, const int* __restrict__ wq,
    const float* __restrict__ scales, const float* __restrict__ bias,
    float* __restrict__ out) {
  const int n = blockIdx.x * 256 + threadIdx.x;
  const int m = blockIdx.y;
  const float* xr = x + (size_t)m * K_DIM;
  const int* wr = wq + (size_t)n * K_DIM;
  float s = 0.f;
  for (int k = 0; k < K_DIM; k += 4) {
    float4 xv = *(const float4*)(xr + k);
    int4  wv = *(const int4*)(wr + k);
    s += xv.x * (float)wv.x + xv.y * (float)wv.y +
         xv.z * (float)wv.z + xv.w * (float)wv.w;
  }
  out[(size_t)m * N_DIM + n] = scales[n] * s + bias[n];
}

extern "C" void kernel_launch(void* const* d_in, const int* in_sizes, int n_in,
                              void* d_out, int out_size, void* d_ws, size_t ws_size,
                              hipStream_t stream) {
  const float* x      = (const float*)d_in[0];
  const int* wq       = (const int*)d_in[1];
  const float* scales = (const float*)d_in[2];
  const float* bias   = (const float*)d_in[3];
  float* out          = (float*)d_out;

  const size_t need4 = (size_t)XP_BYTES + 4 * PART_ELEMS * sizeof(float);
  const size_t need2 = (size_t)XP_BYTES + 2 * PART_ELEMS * sizeof(float);
  int ks = (ws_size >= need4) ? 4 : (ws_size >= need2) ? 2
         : (ws_size >= (size_t)XP_BYTES) ? 1 : 0;
  if (ks == 0) {
    naive_kernel<<<dim3(N_DIM / 256, M_ROWS), 256, 0, stream>>>(x, wq, scales, bias, out);
    return;
  }
  unsigned short* xp = (unsigned short*)d_ws;
  float* part        = (float*)((char*)d_ws + XP_BYTES);

  pack_x_kernel<<<256, 256, 0, stream>>>(x, xp);
  gemm1w_kernel<<<dim3(NT16, ks), 64, 0, stream>>>(
      xp, wq, scales, bias, ks == 1 ? out : part, ks);
  if (ks > 1)
    reduce_kernel<<<dim3((N_DIM / 4 + 255) / 256, M_ROWS), 256, 0, stream>>>(
        part, scales, bias, out, ks);
}